// Round 6
// baseline (2222.566 us; speedup 1.0000x reference)
//
#include <hip/hip_runtime.h>
#include <hip/hip_bf16.h>

// EarthAttention2D on MI355X (gfx950).
// B_WIN=2048, N=128, DIM=512, HEADS=16, hd=32, M = 2048*128 = 262144.
// Pipeline: cvt_x (x->bf16) + prep (weights->bf16, epb gather)
//        -> QKV GEMM (128^2 tile, BK=32, 2-buf issue-early STAGE,
//           quarter-wave-swizzled LDS, 5 blocks/CU;
//           epilogue writes Q/K[b,h,n,d], Vt[b,h,d,n])
//        -> fused window attention (gload_lds Q/K swizzled, padded Vt)
//        -> proj GEMM (same template, f32 out).
//
// LDS swizzle (BK=32, 64B rows): ds_read_b128 quarter-wave (16 lanes, g
// fixed) spreads over all 8 128B bank-groups via slot s' = s ^ ((r>>1)&3);
// GLDS dest stays linear, the global SOURCE carries the inverse swizzle
// (m173).  Verified r5: conflicts 5.56e7 -> 5.2e6.
//
// Occupancy is the binding constraint at K=512 (nk small, no steady-state
// pipeline): r2 5blk/CU=564us > r5 3blk/CU=630us > r3 1blk/CU=718us.
// This round: 5 blocks/CU AND issue-early overlap.

typedef short short8 __attribute__((ext_vector_type(8)));
typedef float f32x4 __attribute__((ext_vector_type(4)));
typedef unsigned short u16;
typedef unsigned int u32;

__device__ __forceinline__ u16 f2bf(float f) {
    __bf16 h = (__bf16)f;                    // RNE fptrunc -> v_cvt on gfx950
    union { __bf16 b; u16 u; } v; v.b = h;
    return v.u;
}

__device__ __forceinline__ f32x4 mfma16(short8 a, short8 b, f32x4 c) {
    return __builtin_amdgcn_mfma_f32_16x16x32_bf16(a, b, c, 0, 0, 0);
}

// async global->LDS, 16B per lane, dest = wave-uniform base + lane*16
#define GLDS16(gsrc, ldst)                                                  \
    __builtin_amdgcn_global_load_lds(                                       \
        (const __attribute__((address_space(1))) void*)(gsrc),              \
        (__attribute__((address_space(3))) void*)(ldst), 16, 0, 0)

// ---------------------------------------------------------------- cvt_x ----
__global__ __launch_bounds__(256) void cvt_x_kernel(
    const float4* __restrict__ xin, int4* __restrict__ xbf)
{
    int idx = blockIdx.x * 256 + threadIdx.x;           // unit = 8 floats
    for (; idx < 16777216; idx += 8192 * 256) {
        const float4 a = xin[idx * 2], b = xin[idx * 2 + 1];
        int4 o;
        o.x = (u32)f2bf(a.x) | ((u32)f2bf(a.y) << 16);
        o.y = (u32)f2bf(a.z) | ((u32)f2bf(a.w) << 16);
        o.z = (u32)f2bf(b.x) | ((u32)f2bf(b.y) << 16);
        o.w = (u32)f2bf(b.z) | ((u32)f2bf(b.w) << 16);
        xbf[idx] = o;
    }
}

// ---------------------------------------------------------------- prep ----
__global__ __launch_bounds__(256) void prep_kernel(
    const float* __restrict__ qkv_w, const float* __restrict__ proj_w,
    const float* __restrict__ btab, const int* __restrict__ pidx,
    u16* __restrict__ qkvw_bf, u16* __restrict__ projw_bf,
    float* __restrict__ epb)
{
    const int i = blockIdx.x * 256 + threadIdx.x;    // grid = 3072*256 = 786432
    qkvw_bf[i] = f2bf(qkv_w[i]);
    if (i < 512 * 512) projw_bf[i] = f2bf(proj_w[i]);
    if (i < 16 * 128 * 128) {
        const int rc = i & 16383, h = i >> 14;
        epb[i] = btab[pidx[rc] * 128 + 64 + h];      // bias_table[idx][TOW/2=4][h]
    }
}

// ---------------------------------------------------------------- GEMM ----
// C[M,Nn] = A[M,K] @ Bt[Nn,K]^T (+bias).  128x128 tile, BK=32, 4 waves.
// LDS: 2 buffers x (A[128][32] + B[128][32]) = 32 KiB -> 5 blocks/CU.
// Loop: STAGE(t+1, buf^1) FIRST (issue-early) -> ds_read+MFMA(t, buf) ->
// vmcnt(0) [loads had the whole compute phase to land] -> s_barrier.
//
// EPI_QKV: per-tile t_sel = bn>>2 (0=Q,1=K,2=V), 4 heads per tile.
//   Q/K: out[((b*16+h)*128 + n)*32 + d] = (acc+bias)*scale  (head-major)
//   V:   out[((b*16+h)*32 + d)*128 + n] = acc+bias          (transposed)
// else: f32 direct stores (+bias) to Cv.

template<bool EPI_QKV>
__global__ __launch_bounds__(256, 5) void gemm_bt(
    const u16* __restrict__ A, const u16* __restrict__ Bt,
    const float* __restrict__ bias, void* __restrict__ Cv,
    u16* __restrict__ kb, u16* __restrict__ vtb,
    const int Nn, const int K, const float qscale)
{
    __shared__ __attribute__((aligned(16))) char sm[32768];

    const int tid = threadIdx.x;
    const int lane = tid & 63;
    const int w = tid >> 6;
    const int lo = lane & 15, g = lane >> 4;
    const int wm = w >> 1, wn = w & 1;
    const int wofs = __builtin_amdgcn_readfirstlane(w) * 1024;
    const int ntile = Nn >> 7;

    int wg = blockIdx.x;
    {   // bijective XCD swizzle (gridDim % 8 == 0 for all launches)
        const int cpx = gridDim.x >> 3;
        wg = (wg & 7) * cpx + (wg >> 3);
    }
    const int bm = wg / ntile, bn = wg % ntile;
    const size_t m0 = (size_t)bm << 7;
    const int n0 = bn << 7;
    const int nk = K >> 5;                               // 16

    // staging: slot sid = tid (rows 0..63) / tid+256 (rows 64..127);
    // row = sid>>2, LDS slot = sid&3, source chunk = (sid&3) ^ ((sid>>3)&3).
    const int rs = tid >> 2;
    const int c8 = (((tid & 3) ^ ((tid >> 3) & 3))) * 8;
    const u16* pa0 = A + (m0 + rs) * (size_t)K + c8;
    const u16* pa1 = pa0 + (size_t)64 * K;
    const u16* pb0 = Bt + (size_t)(n0 + rs) * K + c8;
    const u16* pb1 = pb0 + (size_t)64 * K;

#define STAGE(buf, kt)                                                     \
    do {                                                                   \
        const int ko = (kt) << 5;                                          \
        char* d = sm + (buf) * 16384 + wofs;                               \
        GLDS16(pa0 + ko, d);                                               \
        GLDS16(pa1 + ko, d + 4096);                                        \
        GLDS16(pb0 + ko, d + 8192);                                        \
        GLDS16(pb1 + ko, d + 12288);                                       \
    } while (0)

    f32x4 acc[4][4] = {};

    STAGE(0, 0);
    asm volatile("s_waitcnt vmcnt(0)" ::: "memory");     // tile0 resident
    __builtin_amdgcn_s_barrier();

    // ds_read col swizzle: chunk = g ^ ((lo>>1)&3)  (constant per lane)
    const int csw16 = (g ^ ((lo >> 1) & 3)) << 4;

    int buf = 0;
    for (int t = 0; t < nk; ++t) {
        if (t + 1 < nk) STAGE(buf ^ 1, t + 1);           // issue-early (T14)
        const char* Ab = sm + buf * 16384;
        const char* Bb = Ab + 8192;
        short8 af[4], bq[4];
#pragma unroll
        for (int i = 0; i < 4; ++i) {
            af[i] = *(const short8*)(Ab + (wm * 64 + i * 16 + lo) * 64 + csw16);
            bq[i] = *(const short8*)(Bb + (wn * 64 + i * 16 + lo) * 64 + csw16);
        }
#pragma unroll
        for (int i = 0; i < 4; ++i)
#pragma unroll
            for (int j = 0; j < 4; ++j)
                acc[i][j] = mfma16(af[i], bq[j], acc[i][j]);
        asm volatile("s_waitcnt vmcnt(0)" ::: "memory"); // t+1 landed under MFMA
        asm volatile("" ::: "memory");
        __builtin_amdgcn_s_barrier();
        buf ^= 1;
    }
#undef STAGE

    if constexpr (EPI_QKV) {
        u16* Ct = (u16*)sm;                              // reuse LDS (post-barrier)
        const int b16 = ((int)(m0 >> 7)) * 16;
        const int tsel = bn >> 2;                        // 0=q,1=k,2=v
        const int h0 = (bn & 3) << 2;
        u16* outb = (tsel == 0) ? (u16*)Cv : (tsel == 1) ? kb : vtb;
        if (tsel < 2) {
            // Ct as [128][136] won't fit 32KB -> use [128][128] with the
            // proven r2 pattern: write cols by quarter-wave (c = ...+lo),
            // rows stride 128 u16 = 256B -> quarter-wave lanes hit distinct
            // rows? No: writes are col-major per lane here; keep 136 pad by
            // splitting into two 64-row halves (64*136*2 = 17.4KB fits).
            const float sc = (tsel == 0) ? qscale : 1.0f;
#pragma unroll
            for (int ph = 0; ph < 2; ++ph) {
                __syncthreads();
                if (wm == ph) {
#pragma unroll
                    for (int j = 0; j < 4; ++j) {
                        const int c = wn * 64 + j * 16 + lo;
                        const float bv = bias[n0 + c];
#pragma unroll
                        for (int i = 0; i < 4; ++i)
#pragma unroll
                            for (int ii = 0; ii < 4; ++ii) {
                                const int r = i * 16 + g * 4 + ii;
                                Ct[r * 136 + c] = f2bf((acc[i][j][ii] + bv) * sc);
                            }
                    }
                }
                __syncthreads();
#pragma unroll
                for (int it = 0; it < 4; ++it) {
                    const int idx = it * 256 + tid;
                    const int r = idx >> 4, s2 = idx & 15;
                    const int hl = s2 >> 2, d0 = (s2 & 3) * 8;
                    *(int4*)(outb + ((size_t)(b16 + h0 + hl) * 128
                                     + ph * 64 + r) * 32 + d0) =
                        *(const int4*)(Ct + r * 136 + s2 * 8);
                }
            }
        } else {
            // V: restage transposed -> global [b,h,d,n]; 128 cols x 136 rows
            // split into two 64-col halves.
#pragma unroll
            for (int ph = 0; ph < 2; ++ph) {
                __syncthreads();
                if (wn == ph) {
#pragma unroll
                    for (int j = 0; j < 4; ++j) {
                        const int c = j * 16 + lo;       // 0..63 within half
                        const float bv = bias[n0 + ph * 64 + wn * 0 + c
                                              + ph * 0 + (wn ? 0 : 0)];
                        // (wn==ph) -> global col = wn*64 + c = ph*64 + c
#pragma unroll
                        for (int i = 0; i < 4; ++i)
#pragma unroll
                            for (int ii = 0; ii < 4; ++ii) {
                                const int r = wm * 64 + i * 16 + g * 4 + ii;
                                Ct[c * 136 + r] = f2bf(acc[i][j][ii] + bv);
                            }
                    }
                }
                __syncthreads();
#pragma unroll
                for (int it = 0; it < 4; ++it) {
                    const int idx = it * 256 + tid;
                    const int cidx = idx >> 4, nc = idx & 15;   // cidx 0..63
                    const int gc = ph * 64 + cidx;              // global col
                    const int hl = gc >> 5, d = gc & 31;
                    *(int4*)(outb + ((size_t)(b16 + h0 + hl) * 32 + d) * 128
                             + nc * 8) =
                        *(const int4*)(Ct + cidx * 136 + nc * 8);
                }
            }
        }
    } else {
        float* Cg = (float*)Cv;
#pragma unroll
        for (int j = 0; j < 4; ++j) {
            const int c = wn * 64 + j * 16 + lo;
            const float bv = bias[n0 + c];
#pragma unroll
            for (int i = 0; i < 4; ++i)
#pragma unroll
                for (int ii = 0; ii < 4; ++ii) {
                    const size_t r = m0 + wm * 64 + i * 16 + g * 4 + ii;
                    Cg[r * (size_t)Nn + n0 + c] = acc[i][j][ii] + bv;
                }
        }
    }
}

// ----------------------------------------------------------- attention ----
// One block (4 waves) per (b, h).  Inputs head-major: Q[b,h,n,d], K[b,h,n,d],
// Vt[b,h,d,n].  Q/K staged via global_load_lds with the same quarter-wave
// swizzle as the GEMM (64B rows); Vt reg-staged into padded [32][136].
// Union LDS 43520 B -> 3 blocks/CU.
__global__ __launch_bounds__(256) void attn_kernel(
    const u16* __restrict__ qbuf, const u16* __restrict__ kbuf,
    const u16* __restrict__ vtbuf, const float* __restrict__ epb,
    u16* __restrict__ aout)
{
    __shared__ __attribute__((aligned(16))) char smem[43520];
    u16 (*Vt)[136]      = (u16(*)[136])smem;                 // [32][136]
    char* Qs            = smem + 8704;                       // [128][32] swz
    char* Ks            = smem + 16896;                      // [128][32] swz
    u16 (*Ps)[32][136]  = (u16(*)[32][136])(smem + 8704);    // [4][32][136]
    u16 (*Os)[32]       = (u16(*)[32])smem;                  // [128][32]

    const int h = blockIdx.x >> 11;
    const int b = blockIdx.x & 2047;
    const int tid = threadIdx.x;
    const int lane = tid & 63, w = tid >> 6;
    const int lo = lane & 15, g = lane >> 4;
    const int wu = __builtin_amdgcn_readfirstlane(w);

    const size_t hb = (size_t)(b * 16 + h) * 4096;
    const u16* qp = qbuf + hb;
    const u16* kp = kbuf + hb;
    const u16* vp = vtbuf + hb;

    // Q/K via global_load_lds with inverse-swizzled source
    const int c8 = ((lane & 3) ^ ((lane >> 3) & 3)) * 8;
    const int rofs = (lane >> 2) * 32;
#pragma unroll
    for (int cc = 0; cc < 2; ++cc) {
        const int ch = wu * 2 + cc;
        GLDS16(qp + ch * 512 + rofs + c8, Qs + ch * 1024);
        GLDS16(kp + ch * 512 + rofs + c8, Ks + ch * 1024);
    }
    // Vt: coalesced int4 loads -> padded LDS rows
#pragma unroll
    for (int it = 0; it < 2; ++it) {
        const int idx = tid + it * 256;          // 0..511
        const int d = idx >> 4, nc = idx & 15;
        const int4 v = *(const int4*)(vp + idx * 8);
        *(int4*)(&Vt[d][nc * 8]) = v;
    }
    __syncthreads();

    const int r0 = w * 32;
    const int csw16 = (g ^ ((lo >> 1) & 3)) << 4;   // ds_read col swizzle

    // ---- S = Q @ K^T ----
    short8 aq[2], bk[8];
    aq[0] = *(const short8*)(Qs + (r0 + lo) * 64 + csw16);
    aq[1] = *(const short8*)(Qs + (r0 + 16 + lo) * 64 + csw16);
#pragma unroll
    for (int j = 0; j < 8; ++j)
        bk[j] = *(const short8*)(Ks + (j * 16 + lo) * 64 + csw16);

    f32x4 acc[2][8];
#pragma unroll
    for (int j = 0; j < 8; ++j) {
        f32x4 z = {0.f, 0.f, 0.f, 0.f};
        acc[0][j] = mfma16(aq[0], bk[j], z);
        acc[1][j] = mfma16(aq[1], bk[j], z);
    }

    // ---- bias + row max ----
    const float* eb = epb + (h << 14);
    float mrow[2][4], rsum[2][4];
#pragma unroll
    for (int mt = 0; mt < 2; ++mt)
#pragma unroll
        for (int ii = 0; ii < 4; ++ii) { mrow[mt][ii] = -1e30f; rsum[mt][ii] = 0.f; }

#pragma unroll
    for (int mt = 0; mt < 2; ++mt)
#pragma unroll
        for (int j = 0; j < 8; ++j)
#pragma unroll
            for (int ii = 0; ii < 4; ++ii) {
                const int r = r0 + mt * 16 + g * 4 + ii;
                const int c = j * 16 + lo;
                const float sv = acc[mt][j][ii] + eb[(r << 7) + c];
                acc[mt][j][ii] = sv;
                mrow[mt][ii] = fmaxf(mrow[mt][ii], sv);
            }
#pragma unroll
    for (int d = 1; d < 16; d <<= 1)
#pragma unroll
        for (int mt = 0; mt < 2; ++mt)
#pragma unroll
            for (int ii = 0; ii < 4; ++ii)
                mrow[mt][ii] = fmaxf(mrow[mt][ii], __shfl_xor(mrow[mt][ii], d, 64));

    __syncthreads();   // all waves done reading Qs/Ks -> Ps may overwrite

    // ---- exp -> Ps (per-wave private region), row sums ----
#pragma unroll
    for (int mt = 0; mt < 2; ++mt)
#pragma unroll
        for (int j = 0; j < 8; ++j)
#pragma unroll
            for (int ii = 0; ii < 4; ++ii) {
                const float p = __expf(acc[mt][j][ii] - mrow[mt][ii]);
                rsum[mt][ii] += p;
                Ps[w][mt * 16 + g * 4 + ii][j * 16 + lo] = f2bf(p);
            }
#pragma unroll
    for (int d = 1; d < 16; d <<= 1)
#pragma unroll
        for (int mt = 0; mt < 2; ++mt)
#pragma unroll
            for (int ii = 0; ii < 4; ++ii)
                rsum[mt][ii] += __shfl_xor(rsum[mt][ii], d, 64);

    // ---- O = P @ V ----
    f32x4 o[2][2] = {};
#pragma unroll
    for (int kk = 0; kk < 4; ++kk) {
        short8 av[2];
        av[0] = *(const short8*)(&Ps[w][lo][kk * 32 + g * 8]);
        av[1] = *(const short8*)(&Ps[w][16 + lo][kk * 32 + g * 8]);
#pragma unroll
        for (int dt = 0; dt < 2; ++dt) {
            const short8 bv = *(const short8*)(&Vt[dt * 16 + lo][kk * 32 + g * 8]);
            o[0][dt] = mfma16(av[0], bv, o[0][dt]);
            o[1][dt] = mfma16(av[1], bv, o[1][dt]);
        }
    }

    __syncthreads();   // all waves done reading Vt -> Os may overwrite

    // ---- normalize -> Os, coalesced int4 stores ----
#pragma unroll
    for (int mt = 0; mt < 2; ++mt)
#pragma unroll
        for (int dt = 0; dt < 2; ++dt)
#pragma unroll
            for (int ii = 0; ii < 4; ++ii)
                Os[r0 + mt * 16 + g * 4 + ii][dt * 16 + lo] =
                    f2bf(o[mt][dt][ii] / rsum[mt][ii]);
    __syncthreads();

    u16* op = aout + (size_t)b * 128 * 512 + h * 32;
#pragma unroll
    for (int it = 0; it < 2; ++it) {
        const int idx = tid + it * 256;          // 0..511
        const int r = idx >> 2, c = (idx & 3) * 8;
        *(int4*)(op + (size_t)r * 512 + c) = *(const int4*)(&Os[r][c]);
    }
}

// -------------------------------------------------------------- launch ----
extern "C" void kernel_launch(void* const* d_in, const int* in_sizes, int n_in,
                              void* d_out, int out_size, void* d_ws, size_t ws_size,
                              hipStream_t stream)
{
    const float* x      = (const float*)d_in[0];
    const float* qkv_w  = (const float*)d_in[1];
    const float* qkv_b  = (const float*)d_in[2];
    const float* proj_w = (const float*)d_in[3];
    const float* proj_b = (const float*)d_in[4];
    const float* btab   = (const float*)d_in[5];
    const int*   pidx   = (const int*)d_in[6];

    // workspace layout (bytes), total 1,076,887,552
    // xbf aliases attnbuf: x_bf16 is dead before attn writes its output.
    char* ws = (char*)d_ws;
    u16*   xbf      = (u16*)(ws);                        // 268,435,456
    u16*   attnbuf  = (u16*)(ws);                        // (alias)
    u16*   qkvw_bf  = (u16*)(ws + 268435456);            //   1,572,864
    u16*   projw_bf = (u16*)(ws + 270008320);            //     524,288
    float* epb      = (float*)(ws + 270532608);          //   1,048,576
    u16*   qbuf     = (u16*)(ws + 271581184);            // 268,435,456
    u16*   kbuf     = (u16*)(ws + 540016640);            // 268,435,456
    u16*   vtbuf    = (u16*)(ws + 808452096);            // 268,435,456

    const float qscale = 0.17677669529663687f;           // 32^-0.5

    cvt_x_kernel<<<dim3(8192), dim3(256), 0, stream>>>(
        (const float4*)x, (int4*)xbf);

    prep_kernel<<<dim3(3072), dim3(256), 0, stream>>>(
        qkv_w, proj_w, btab, pidx, qkvw_bf, projw_bf, epb);

    // QKV: [262144,512]bf16 @ [1536,512]bf16^T -> Q/K/Vt head-major buffers
    gemm_bt<true><<<dim3(2048 * 12), dim3(256), 0, stream>>>(
        xbf, qkvw_bf, qkv_b, qbuf, kbuf, vtbuf, 1536, 512, qscale);

    // fused window attention: 2048 windows x 16 heads
    attn_kernel<<<dim3(32768), dim3(256), 0, stream>>>(
        qbuf, kbuf, vtbuf, epb, attnbuf);

    // proj: [262144,512]bf16 @ [512,512]bf16^T -> f32 (+bias)
    gemm_bt<false><<<dim3(2048 * 4), dim3(256), 0, stream>>>(
        attnbuf, projw_bf, proj_b, d_out, nullptr, nullptr, 512, 512, 1.0f);
}

// Round 7
// 1447.895 us; speedup vs baseline: 1.5350x; 1.5350x over previous
//
#include <hip/hip_runtime.h>
#include <hip/hip_bf16.h>

// EarthAttention2D on MI355X (gfx950).
// B_WIN=2048, N=128, DIM=512, HEADS=16, hd=32, M = 2048*128 = 262144.
// Pipeline: cvt_x (x->bf16) + prep (weights->bf16, epb gather)
//        -> QKV GEMM (128^2 tile, BK=32, 2-buf issue-early STAGE,
//           quarter-wave-swizzled LDS; epilogue writes Q/K[b,h,n,d], Vt[b,h,d,n])
//        -> fused window attention (gload_lds Q/K swizzled, padded Vt)
//        -> proj GEMM (same template, f32 out).
//
// ROUND-6 POST-MORTEM: __launch_bounds__(256,5) capped VGPR at 48 < 64
// needed for acc[4][4] -> accumulator spilled to scratch (WRITE_SIZE 3x,
// hbm_bytes +1.7GB, dur 2x). NEVER pin min-waves above the working set.
// This round: identical kernel, plain __launch_bounds__(256).
//
// LDS swizzle (BK=32, 64B rows): ds_read_b128 quarter-wave spreads over
// all 8 128B bank-groups via slot s' = s ^ ((r>>1)&3); GLDS dest linear,
// global SOURCE carries the inverse swizzle (m173). Verified r5:
// conflicts 5.56e7 -> 5.2e6.

typedef short short8 __attribute__((ext_vector_type(8)));
typedef float f32x4 __attribute__((ext_vector_type(4)));
typedef unsigned short u16;
typedef unsigned int u32;

__device__ __forceinline__ u16 f2bf(float f) {
    __bf16 h = (__bf16)f;                    // RNE fptrunc -> v_cvt on gfx950
    union { __bf16 b; u16 u; } v; v.b = h;
    return v.u;
}

__device__ __forceinline__ f32x4 mfma16(short8 a, short8 b, f32x4 c) {
    return __builtin_amdgcn_mfma_f32_16x16x32_bf16(a, b, c, 0, 0, 0);
}

// async global->LDS, 16B per lane, dest = wave-uniform base + lane*16
#define GLDS16(gsrc, ldst)                                                  \
    __builtin_amdgcn_global_load_lds(                                       \
        (const __attribute__((address_space(1))) void*)(gsrc),              \
        (__attribute__((address_space(3))) void*)(ldst), 16, 0, 0)

// ---------------------------------------------------------------- cvt_x ----
__global__ __launch_bounds__(256) void cvt_x_kernel(
    const float4* __restrict__ xin, int4* __restrict__ xbf)
{
    int idx = blockIdx.x * 256 + threadIdx.x;           // unit = 8 floats
    for (; idx < 16777216; idx += 8192 * 256) {
        const float4 a = xin[idx * 2], b = xin[idx * 2 + 1];
        int4 o;
        o.x = (u32)f2bf(a.x) | ((u32)f2bf(a.y) << 16);
        o.y = (u32)f2bf(a.z) | ((u32)f2bf(a.w) << 16);
        o.z = (u32)f2bf(b.x) | ((u32)f2bf(b.y) << 16);
        o.w = (u32)f2bf(b.z) | ((u32)f2bf(b.w) << 16);
        xbf[idx] = o;
    }
}

// ---------------------------------------------------------------- prep ----
__global__ __launch_bounds__(256) void prep_kernel(
    const float* __restrict__ qkv_w, const float* __restrict__ proj_w,
    const float* __restrict__ btab, const int* __restrict__ pidx,
    u16* __restrict__ qkvw_bf, u16* __restrict__ projw_bf,
    float* __restrict__ epb)
{
    const int i = blockIdx.x * 256 + threadIdx.x;    // grid = 3072*256 = 786432
    qkvw_bf[i] = f2bf(qkv_w[i]);
    if (i < 512 * 512) projw_bf[i] = f2bf(proj_w[i]);
    if (i < 16 * 128 * 128) {
        const int rc = i & 16383, h = i >> 14;
        epb[i] = btab[pidx[rc] * 128 + 64 + h];      // bias_table[idx][TOW/2=4][h]
    }
}

// ---------------------------------------------------------------- GEMM ----
// C[M,Nn] = A[M,K] @ Bt[Nn,K]^T (+bias).  128x128 tile, BK=32, 4 waves.
// LDS: 2 buffers x (A[128][32] + B[128][32]) = 32 KiB -> 5 blocks/CU.
// Loop: STAGE(t+1, buf^1) FIRST (issue-early) -> ds_read+MFMA(t, buf) ->
// vmcnt(0) [loads had the whole compute phase to land] -> s_barrier.
//
// EPI_QKV: per-tile t_sel = bn>>2 (0=Q,1=K,2=V), 4 heads per tile.
//   Q/K: out[((b*16+h)*128 + n)*32 + d] = (acc+bias)*scale  (head-major)
//   V:   out[((b*16+h)*32 + d)*128 + n] = acc+bias          (transposed)
// else: f32 direct stores (+bias) to Cv.

template<bool EPI_QKV>
__global__ __launch_bounds__(256) void gemm_bt(
    const u16* __restrict__ A, const u16* __restrict__ Bt,
    const float* __restrict__ bias, void* __restrict__ Cv,
    u16* __restrict__ kb, u16* __restrict__ vtb,
    const int Nn, const int K, const float qscale)
{
    __shared__ __attribute__((aligned(16))) char sm[32768];

    const int tid = threadIdx.x;
    const int lane = tid & 63;
    const int w = tid >> 6;
    const int lo = lane & 15, g = lane >> 4;
    const int wm = w >> 1, wn = w & 1;
    const int wofs = __builtin_amdgcn_readfirstlane(w) * 1024;
    const int ntile = Nn >> 7;

    int wg = blockIdx.x;
    {   // bijective XCD swizzle (gridDim % 8 == 0 for all launches)
        const int cpx = gridDim.x >> 3;
        wg = (wg & 7) * cpx + (wg >> 3);
    }
    const int bm = wg / ntile, bn = wg % ntile;
    const size_t m0 = (size_t)bm << 7;
    const int n0 = bn << 7;
    const int nk = K >> 5;                               // 16

    // staging: slot sid = tid (rows 0..63) / tid+256 (rows 64..127);
    // row = sid>>2, LDS slot = sid&3, source chunk = (sid&3) ^ ((sid>>3)&3).
    const int rs = tid >> 2;
    const int c8 = (((tid & 3) ^ ((tid >> 3) & 3))) * 8;
    const u16* pa0 = A + (m0 + rs) * (size_t)K + c8;
    const u16* pa1 = pa0 + (size_t)64 * K;
    const u16* pb0 = Bt + (size_t)(n0 + rs) * K + c8;
    const u16* pb1 = pb0 + (size_t)64 * K;

#define STAGE(buf, kt)                                                     \
    do {                                                                   \
        const int ko = (kt) << 5;                                          \
        char* d = sm + (buf) * 16384 + wofs;                               \
        GLDS16(pa0 + ko, d);                                               \
        GLDS16(pa1 + ko, d + 4096);                                        \
        GLDS16(pb0 + ko, d + 8192);                                        \
        GLDS16(pb1 + ko, d + 12288);                                       \
    } while (0)

    f32x4 acc[4][4] = {};

    STAGE(0, 0);
    asm volatile("s_waitcnt vmcnt(0)" ::: "memory");     // tile0 resident
    __builtin_amdgcn_s_barrier();

    // ds_read col swizzle: chunk = g ^ ((lo>>1)&3)  (constant per lane)
    const int csw16 = (g ^ ((lo >> 1) & 3)) << 4;

    int buf = 0;
    for (int t = 0; t < nk; ++t) {
        if (t + 1 < nk) STAGE(buf ^ 1, t + 1);           // issue-early (T14)
        const char* Ab = sm + buf * 16384;
        const char* Bb = Ab + 8192;
        short8 af[4], bq[4];
#pragma unroll
        for (int i = 0; i < 4; ++i) {
            af[i] = *(const short8*)(Ab + (wm * 64 + i * 16 + lo) * 64 + csw16);
            bq[i] = *(const short8*)(Bb + (wn * 64 + i * 16 + lo) * 64 + csw16);
        }
#pragma unroll
        for (int i = 0; i < 4; ++i)
#pragma unroll
            for (int j = 0; j < 4; ++j)
                acc[i][j] = mfma16(af[i], bq[j], acc[i][j]);
        asm volatile("s_waitcnt vmcnt(0)" ::: "memory"); // t+1 landed under MFMA
        asm volatile("" ::: "memory");
        __builtin_amdgcn_s_barrier();
        buf ^= 1;
    }
#undef STAGE

    if constexpr (EPI_QKV) {
        u16* Ct = (u16*)sm;                              // reuse LDS (post-barrier)
        const int b16 = ((int)(m0 >> 7)) * 16;
        const int tsel = bn >> 2;                        // 0=q,1=k,2=v
        const int h0 = (bn & 3) << 2;
        u16* outb = (tsel == 0) ? (u16*)Cv : (tsel == 1) ? kb : vtb;
        if (tsel < 2) {
            // two 64-row halves through padded [64][136] LDS (17.4 KB)
            const float sc = (tsel == 0) ? qscale : 1.0f;
#pragma unroll
            for (int ph = 0; ph < 2; ++ph) {
                __syncthreads();
                if (wm == ph) {
#pragma unroll
                    for (int j = 0; j < 4; ++j) {
                        const int c = wn * 64 + j * 16 + lo;
                        const float bv = bias[n0 + c];
#pragma unroll
                        for (int i = 0; i < 4; ++i)
#pragma unroll
                            for (int ii = 0; ii < 4; ++ii) {
                                const int r = i * 16 + g * 4 + ii;
                                Ct[r * 136 + c] = f2bf((acc[i][j][ii] + bv) * sc);
                            }
                    }
                }
                __syncthreads();
#pragma unroll
                for (int it = 0; it < 4; ++it) {
                    const int idx = it * 256 + tid;
                    const int r = idx >> 4, s2 = idx & 15;
                    const int hl = s2 >> 2, d0 = (s2 & 3) * 8;
                    *(int4*)(outb + ((size_t)(b16 + h0 + hl) * 128
                                     + ph * 64 + r) * 32 + d0) =
                        *(const int4*)(Ct + r * 136 + s2 * 8);
                }
            }
        } else {
            // V: restage transposed -> global [b,h,d,n]; two 64-col halves.
#pragma unroll
            for (int ph = 0; ph < 2; ++ph) {
                __syncthreads();
                if (wn == ph) {
#pragma unroll
                    for (int j = 0; j < 4; ++j) {
                        const int c = j * 16 + lo;       // 0..63 within half
                        const float bv = bias[n0 + ph * 64 + c];
#pragma unroll
                        for (int i = 0; i < 4; ++i)
#pragma unroll
                            for (int ii = 0; ii < 4; ++ii) {
                                const int r = wm * 64 + i * 16 + g * 4 + ii;
                                Ct[c * 136 + r] = f2bf(acc[i][j][ii] + bv);
                            }
                    }
                }
                __syncthreads();
#pragma unroll
                for (int it = 0; it < 4; ++it) {
                    const int idx = it * 256 + tid;
                    const int cidx = idx >> 4, nc = idx & 15;   // cidx 0..63
                    const int gc = ph * 64 + cidx;              // global col
                    const int hl = gc >> 5, d = gc & 31;
                    *(int4*)(outb + ((size_t)(b16 + h0 + hl) * 32 + d) * 128
                             + nc * 8) =
                        *(const int4*)(Ct + cidx * 136 + nc * 8);
                }
            }
        }
    } else {
        float* Cg = (float*)Cv;
#pragma unroll
        for (int j = 0; j < 4; ++j) {
            const int c = wn * 64 + j * 16 + lo;
            const float bv = bias[n0 + c];
#pragma unroll
            for (int i = 0; i < 4; ++i)
#pragma unroll
                for (int ii = 0; ii < 4; ++ii) {
                    const size_t r = m0 + wm * 64 + i * 16 + g * 4 + ii;
                    Cg[r * (size_t)Nn + n0 + c] = acc[i][j][ii] + bv;
                }
        }
    }
}

// ----------------------------------------------------------- attention ----
// One block (4 waves) per (b, h).  Inputs head-major: Q[b,h,n,d], K[b,h,n,d],
// Vt[b,h,d,n].  Q/K staged via global_load_lds with the same quarter-wave
// swizzle as the GEMM (64B rows); Vt reg-staged into padded [32][136].
// Union LDS 43520 B -> 3 blocks/CU.
__global__ __launch_bounds__(256) void attn_kernel(
    const u16* __restrict__ qbuf, const u16* __restrict__ kbuf,
    const u16* __restrict__ vtbuf, const float* __restrict__ epb,
    u16* __restrict__ aout)
{
    __shared__ __attribute__((aligned(16))) char smem[43520];
    u16 (*Vt)[136]      = (u16(*)[136])smem;                 // [32][136]
    char* Qs            = smem + 8704;                       // [128][32] swz
    char* Ks            = smem + 16896;                      // [128][32] swz
    u16 (*Ps)[32][136]  = (u16(*)[32][136])(smem + 8704);    // [4][32][136]
    u16 (*Os)[32]       = (u16(*)[32])smem;                  // [128][32]

    const int h = blockIdx.x >> 11;
    const int b = blockIdx.x & 2047;
    const int tid = threadIdx.x;
    const int lane = tid & 63, w = tid >> 6;
    const int lo = lane & 15, g = lane >> 4;
    const int wu = __builtin_amdgcn_readfirstlane(w);

    const size_t hb = (size_t)(b * 16 + h) * 4096;
    const u16* qp = qbuf + hb;
    const u16* kp = kbuf + hb;
    const u16* vp = vtbuf + hb;

    // Q/K via global_load_lds with inverse-swizzled source
    const int c8 = ((lane & 3) ^ ((lane >> 3) & 3)) * 8;
    const int rofs = (lane >> 2) * 32;
#pragma unroll
    for (int cc = 0; cc < 2; ++cc) {
        const int ch = wu * 2 + cc;
        GLDS16(qp + ch * 512 + rofs + c8, Qs + ch * 1024);
        GLDS16(kp + ch * 512 + rofs + c8, Ks + ch * 1024);
    }
    // Vt: coalesced int4 loads -> padded LDS rows
#pragma unroll
    for (int it = 0; it < 2; ++it) {
        const int idx = tid + it * 256;          // 0..511
        const int d = idx >> 4, nc = idx & 15;
        const int4 v = *(const int4*)(vp + idx * 8);
        *(int4*)(&Vt[d][nc * 8]) = v;
    }
    __syncthreads();

    const int r0 = w * 32;
    const int csw16 = (g ^ ((lo >> 1) & 3)) << 4;   // ds_read col swizzle

    // ---- S = Q @ K^T ----
    short8 aq[2], bk[8];
    aq[0] = *(const short8*)(Qs + (r0 + lo) * 64 + csw16);
    aq[1] = *(const short8*)(Qs + (r0 + 16 + lo) * 64 + csw16);
#pragma unroll
    for (int j = 0; j < 8; ++j)
        bk[j] = *(const short8*)(Ks + (j * 16 + lo) * 64 + csw16);

    f32x4 acc[2][8];
#pragma unroll
    for (int j = 0; j < 8; ++j) {
        f32x4 z = {0.f, 0.f, 0.f, 0.f};
        acc[0][j] = mfma16(aq[0], bk[j], z);
        acc[1][j] = mfma16(aq[1], bk[j], z);
    }

    // ---- bias + row max ----
    const float* eb = epb + (h << 14);
    float mrow[2][4], rsum[2][4];
#pragma unroll
    for (int mt = 0; mt < 2; ++mt)
#pragma unroll
        for (int ii = 0; ii < 4; ++ii) { mrow[mt][ii] = -1e30f; rsum[mt][ii] = 0.f; }

#pragma unroll
    for (int mt = 0; mt < 2; ++mt)
#pragma unroll
        for (int j = 0; j < 8; ++j)
#pragma unroll
            for (int ii = 0; ii < 4; ++ii) {
                const int r = r0 + mt * 16 + g * 4 + ii;
                const int c = j * 16 + lo;
                const float sv = acc[mt][j][ii] + eb[(r << 7) + c];
                acc[mt][j][ii] = sv;
                mrow[mt][ii] = fmaxf(mrow[mt][ii], sv);
            }
#pragma unroll
    for (int d = 1; d < 16; d <<= 1)
#pragma unroll
        for (int mt = 0; mt < 2; ++mt)
#pragma unroll
            for (int ii = 0; ii < 4; ++ii)
                mrow[mt][ii] = fmaxf(mrow[mt][ii], __shfl_xor(mrow[mt][ii], d, 64));

    __syncthreads();   // all waves done reading Qs/Ks -> Ps may overwrite

    // ---- exp -> Ps (per-wave private region), row sums ----
#pragma unroll
    for (int mt = 0; mt < 2; ++mt)
#pragma unroll
        for (int j = 0; j < 8; ++j)
#pragma unroll
            for (int ii = 0; ii < 4; ++ii) {
                const float p = __expf(acc[mt][j][ii] - mrow[mt][ii]);
                rsum[mt][ii] += p;
                Ps[w][mt * 16 + g * 4 + ii][j * 16 + lo] = f2bf(p);
            }
#pragma unroll
    for (int d = 1; d < 16; d <<= 1)
#pragma unroll
        for (int mt = 0; mt < 2; ++mt)
#pragma unroll
            for (int ii = 0; ii < 4; ++ii)
                rsum[mt][ii] += __shfl_xor(rsum[mt][ii], d, 64);

    // ---- O = P @ V ----
    f32x4 o[2][2] = {};
#pragma unroll
    for (int kk = 0; kk < 4; ++kk) {
        short8 av[2];
        av[0] = *(const short8*)(&Ps[w][lo][kk * 32 + g * 8]);
        av[1] = *(const short8*)(&Ps[w][16 + lo][kk * 32 + g * 8]);
#pragma unroll
        for (int dt = 0; dt < 2; ++dt) {
            const short8 bv = *(const short8*)(&Vt[dt * 16 + lo][kk * 32 + g * 8]);
            o[0][dt] = mfma16(av[0], bv, o[0][dt]);
            o[1][dt] = mfma16(av[1], bv, o[1][dt]);
        }
    }

    __syncthreads();   // all waves done reading Vt -> Os may overwrite

    // ---- normalize -> Os, coalesced int4 stores ----
#pragma unroll
    for (int mt = 0; mt < 2; ++mt)
#pragma unroll
        for (int dt = 0; dt < 2; ++dt)
#pragma unroll
            for (int ii = 0; ii < 4; ++ii)
                Os[r0 + mt * 16 + g * 4 + ii][dt * 16 + lo] =
                    f2bf(o[mt][dt][ii] / rsum[mt][ii]);
    __syncthreads();

    u16* op = aout + (size_t)b * 128 * 512 + h * 32;
#pragma unroll
    for (int it = 0; it < 2; ++it) {
        const int idx = tid + it * 256;          // 0..511
        const int r = idx >> 2, c = (idx & 3) * 8;
        *(int4*)(op + (size_t)r * 512 + c) = *(const int4*)(&Os[r][c]);
    }
}

// -------------------------------------------------------------- launch ----
extern "C" void kernel_launch(void* const* d_in, const int* in_sizes, int n_in,
                              void* d_out, int out_size, void* d_ws, size_t ws_size,
                              hipStream_t stream)
{
    const float* x      = (const float*)d_in[0];
    const float* qkv_w  = (const float*)d_in[1];
    const float* qkv_b  = (const float*)d_in[2];
    const float* proj_w = (const float*)d_in[3];
    const float* proj_b = (const float*)d_in[4];
    const float* btab   = (const float*)d_in[5];
    const int*   pidx   = (const int*)d_in[6];

    // workspace layout (bytes), total 1,076,887,552
    // xbf aliases attnbuf: x_bf16 is dead before attn writes its output.
    char* ws = (char*)d_ws;
    u16*   xbf      = (u16*)(ws);                        // 268,435,456
    u16*   attnbuf  = (u16*)(ws);                        // (alias)
    u16*   qkvw_bf  = (u16*)(ws + 268435456);            //   1,572,864
    u16*   projw_bf = (u16*)(ws + 270008320);            //     524,288
    float* epb      = (float*)(ws + 270532608);          //   1,048,576
    u16*   qbuf     = (u16*)(ws + 271581184);            // 268,435,456
    u16*   kbuf     = (u16*)(ws + 540016640);            // 268,435,456
    u16*   vtbuf    = (u16*)(ws + 808452096);            // 268,435,456

    const float qscale = 0.17677669529663687f;           // 32^-0.5

    cvt_x_kernel<<<dim3(8192), dim3(256), 0, stream>>>(
        (const float4*)x, (int4*)xbf);

    prep_kernel<<<dim3(3072), dim3(256), 0, stream>>>(
        qkv_w, proj_w, btab, pidx, qkvw_bf, projw_bf, epb);

    // QKV: [262144,512]bf16 @ [1536,512]bf16^T -> Q/K/Vt head-major buffers
    gemm_bt<true><<<dim3(2048 * 12), dim3(256), 0, stream>>>(
        xbf, qkvw_bf, qkv_b, qbuf, kbuf, vtbuf, 1536, 512, qscale);

    // fused window attention: 2048 windows x 16 heads
    attn_kernel<<<dim3(32768), dim3(256), 0, stream>>>(
        qbuf, kbuf, vtbuf, epb, attnbuf);

    // proj: [262144,512]bf16 @ [512,512]bf16^T -> f32 (+bias)
    gemm_bt<false><<<dim3(2048 * 4), dim3(256), 0, stream>>>(
        attnbuf, projw_bf, proj_b, d_out, nullptr, nullptr, 512, 512, 1.0f);
}

// Round 8
// 1399.799 us; speedup vs baseline: 1.5878x; 1.0344x over previous
//
#include <hip/hip_runtime.h>
#include <hip/hip_bf16.h>

// EarthAttention2D on MI355X (gfx950).
// B_WIN=2048, N=128, DIM=512, HEADS=16, hd=32, M = 2048*128 = 262144.
// Pipeline: cvt_x (x->bf16) + prep (weights->bf16, epb gather)
//        -> QKV GEMM (r2-proven loop: BK=64, single 32KiB buffer, GLDS both
//           operands, XOR-swizzled reads; head-major epilogue Q/K[b,h,n,d],
//           Vt[b,h,d,n])
//        -> fused window attention (gload_lds Q/K swizzled, padded Vt)
//        -> proj GEMM (same loop, f32 out).
//
// SCHEDULE HISTORY (QKV dispatch): r2 BK=64/1buf/2sync = 564us BEST;
// r5 BK=32/3buf/vmcnt(4) = 630; r7 BK=32/2buf/vmcnt(0) = 744;
// r3 256^2 8-phase = 718; r6 launch_bounds(,5) spill = 1300.
// Lesson: at K=512 (nk=8) this is latency-bound; LDS-footprint (blocks/CU)
// dominates schedule sophistication. vmcnt(0)-after-issue defeats prefetch.
//
// LDS swizzle (BK=64, 128B rows): LDS[r][c16] = global[r][c16^(r&7)]
// (inverse swizzle on the GLDS *source*, linear dest - m173);
// ds_read addr (r*128+cb)^((r&7)<<4) -> quarter-wave hits all 8 bank
// groups twice = conflict-free.

typedef short short8 __attribute__((ext_vector_type(8)));
typedef float f32x4 __attribute__((ext_vector_type(4)));
typedef unsigned short u16;
typedef unsigned int u32;

__device__ __forceinline__ u16 f2bf(float f) {
    __bf16 h = (__bf16)f;                    // RNE fptrunc -> v_cvt on gfx950
    union { __bf16 b; u16 u; } v; v.b = h;
    return v.u;
}

__device__ __forceinline__ f32x4 mfma16(short8 a, short8 b, f32x4 c) {
    return __builtin_amdgcn_mfma_f32_16x16x32_bf16(a, b, c, 0, 0, 0);
}

// async global->LDS, 16B per lane, dest = wave-uniform base + lane*16
#define GLDS16(gsrc, ldst)                                                  \
    __builtin_amdgcn_global_load_lds(                                       \
        (const __attribute__((address_space(1))) void*)(gsrc),              \
        (__attribute__((address_space(3))) void*)(ldst), 16, 0, 0)

// ---------------------------------------------------------------- cvt_x ----
__global__ __launch_bounds__(256) void cvt_x_kernel(
    const float4* __restrict__ xin, int4* __restrict__ xbf)
{
    int idx = blockIdx.x * 256 + threadIdx.x;           // unit = 8 floats
    for (; idx < 16777216; idx += 8192 * 256) {
        const float4 a = xin[idx * 2], b = xin[idx * 2 + 1];
        int4 o;
        o.x = (u32)f2bf(a.x) | ((u32)f2bf(a.y) << 16);
        o.y = (u32)f2bf(a.z) | ((u32)f2bf(a.w) << 16);
        o.z = (u32)f2bf(b.x) | ((u32)f2bf(b.y) << 16);
        o.w = (u32)f2bf(b.z) | ((u32)f2bf(b.w) << 16);
        xbf[idx] = o;
    }
}

// ---------------------------------------------------------------- prep ----
__global__ __launch_bounds__(256) void prep_kernel(
    const float* __restrict__ qkv_w, const float* __restrict__ proj_w,
    const float* __restrict__ btab, const int* __restrict__ pidx,
    u16* __restrict__ qkvw_bf, u16* __restrict__ projw_bf,
    float* __restrict__ epb)
{
    const int i = blockIdx.x * 256 + threadIdx.x;    // grid = 3072*256 = 786432
    qkvw_bf[i] = f2bf(qkv_w[i]);
    if (i < 512 * 512) projw_bf[i] = f2bf(proj_w[i]);
    if (i < 16 * 128 * 128) {
        const int rc = i & 16383, h = i >> 14;
        epb[i] = btab[pidx[rc] * 128 + 64 + h];      // bias_table[idx][TOW/2=4][h]
    }
}

// ---------------------------------------------------------------- GEMM ----
// C[M,Nn] = A[M,K] @ Bt[Nn,K]^T (+bias).  128x128 tile, BK=64, 4 waves.
// LDS: single buffer A[128][64] + B[128][64] = 32 KiB.
// Loop (r2-proven): STAGE(0); { sync(drain); ds_read+32 MFMA; sync; STAGE }.
//
// EPI_QKV: per-tile t_sel = bn>>2 (0=Q,1=K,2=V), 4 heads per tile.
//   Q/K: out[((b*16+h)*128 + n)*32 + d] = (acc+bias)*scale  (head-major)
//   V:   out[((b*16+h)*32 + d)*128 + n] = acc+bias          (transposed)
// else: f32 direct stores (+bias) to Cv.

template<bool EPI_QKV>
__global__ __launch_bounds__(256) void gemm_bt(
    const u16* __restrict__ A, const u16* __restrict__ Bt,
    const float* __restrict__ bias, void* __restrict__ Cv,
    u16* __restrict__ kb, u16* __restrict__ vtb,
    const int Nn, const int K, const float qscale)
{
    __shared__ __attribute__((aligned(16))) char sm[32768];
    char* As = sm;                  // [128] rows x 128B, swizzled content
    char* Bs = sm + 16384;

    const int tid = threadIdx.x;
    const int lane = tid & 63;
    const int w = tid >> 6;
    const int lo = lane & 15, g = lane >> 4;
    const int wm = w >> 1, wn = w & 1;
    const int wofs = __builtin_amdgcn_readfirstlane(w) * 1024;
    const int ntile = Nn >> 7;

    int wg = blockIdx.x;
    {   // bijective XCD swizzle (gridDim % 8 == 0 for all launches)
        const int cpx = gridDim.x >> 3;
        wg = (wg & 7) * cpx + (wg >> 3);
    }
    const int bm = wg / ntile, bn = wg % ntile;
    const size_t m0 = (size_t)bm << 7;
    const int n0 = bn << 7;
    const int nk = K >> 6;                               // 8

    // per-lane global source pointers: slot s = i*256+tid; r=s>>3, c16=s&7;
    // source col-chunk = c16 ^ (r&7)  (inverse swizzle, m173 pattern)
    const u16* pa[4];
    const u16* pb[4];
#pragma unroll
    for (int i = 0; i < 4; ++i) {
        const int s = i * 256 + tid;
        const int r = s >> 3, c16 = s & 7;
        const int csw = (c16 ^ (r & 7)) << 3;            // element offset
        pa[i] = A + (m0 + r) * (size_t)K + csw;
        pb[i] = Bt + (size_t)(n0 + r) * K + csw;
    }

#define STAGE(kt)                                                          \
    do {                                                                   \
        const int koff = (kt) * 64;                                        \
        _Pragma("unroll")                                                  \
        for (int i = 0; i < 4; ++i)                                        \
            GLDS16(pa[i] + koff, As + i * 4096 + wofs);                    \
        _Pragma("unroll")                                                  \
        for (int i = 0; i < 4; ++i)                                        \
            GLDS16(pb[i] + koff, Bs + i * 4096 + wofs);                    \
    } while (0)

    f32x4 acc[4][4] = {};

    STAGE(0);
    for (int kt = 0;;) {
        __syncthreads();            // drains vmcnt -> tile kt resident
#pragma unroll
        for (int kk = 0; kk < 2; ++kk) {
            short8 af[4], bq[4];
            const int cb = (kk * 4 + g) << 4;            // byte col-chunk
            const int sz = (lo & 7) << 4;                // row XOR swizzle
#pragma unroll
            for (int i = 0; i < 4; ++i) {
                const int ra = wm * 64 + i * 16 + lo;
                af[i] = *(const short8*)(As + ((ra * 128 + cb) ^ sz));
                const int rb = wn * 64 + i * 16 + lo;
                bq[i] = *(const short8*)(Bs + ((rb * 128 + cb) ^ sz));
            }
#pragma unroll
            for (int i = 0; i < 4; ++i)
#pragma unroll
                for (int j = 0; j < 4; ++j)
                    acc[i][j] = mfma16(af[i], bq[j], acc[i][j]);
        }
        if (++kt == nk) break;
        __syncthreads();            // all reads done; LDS free for next tile
        STAGE(kt);
    }
#undef STAGE

    if constexpr (EPI_QKV) {
        u16* Ct = (u16*)sm;                              // reuse LDS
        const int b16 = ((int)(m0 >> 7)) * 16;
        const int tsel = bn >> 2;                        // 0=q,1=k,2=v
        const int h0 = (bn & 3) << 2;
        u16* outb = (tsel == 0) ? (u16*)Cv : (tsel == 1) ? kb : vtb;
        if (tsel < 2) {
            // two 64-row halves through padded [64][136] LDS (17.4 KB)
            const float sc = (tsel == 0) ? qscale : 1.0f;
#pragma unroll
            for (int ph = 0; ph < 2; ++ph) {
                __syncthreads();
                if (wm == ph) {
#pragma unroll
                    for (int j = 0; j < 4; ++j) {
                        const int c = wn * 64 + j * 16 + lo;
                        const float bv = bias[n0 + c];
#pragma unroll
                        for (int i = 0; i < 4; ++i)
#pragma unroll
                            for (int ii = 0; ii < 4; ++ii) {
                                const int r = i * 16 + g * 4 + ii;
                                Ct[r * 136 + c] = f2bf((acc[i][j][ii] + bv) * sc);
                            }
                    }
                }
                __syncthreads();
#pragma unroll
                for (int it = 0; it < 4; ++it) {
                    const int idx = it * 256 + tid;
                    const int r = idx >> 4, s2 = idx & 15;
                    const int hl = s2 >> 2, d0 = (s2 & 3) * 8;
                    *(int4*)(outb + ((size_t)(b16 + h0 + hl) * 128
                                     + ph * 64 + r) * 32 + d0) =
                        *(const int4*)(Ct + r * 136 + s2 * 8);
                }
            }
        } else {
            // V: restage transposed -> global [b,h,d,n]; two 64-col halves.
#pragma unroll
            for (int ph = 0; ph < 2; ++ph) {
                __syncthreads();
                if (wn == ph) {
#pragma unroll
                    for (int j = 0; j < 4; ++j) {
                        const int c = j * 16 + lo;       // 0..63 within half
                        const float bv = bias[n0 + ph * 64 + c];
#pragma unroll
                        for (int i = 0; i < 4; ++i)
#pragma unroll
                            for (int ii = 0; ii < 4; ++ii) {
                                const int r = wm * 64 + i * 16 + g * 4 + ii;
                                Ct[c * 136 + r] = f2bf(acc[i][j][ii] + bv);
                            }
                    }
                }
                __syncthreads();
#pragma unroll
                for (int it = 0; it < 4; ++it) {
                    const int idx = it * 256 + tid;
                    const int cidx = idx >> 4, nc = idx & 15;   // cidx 0..63
                    const int gc = ph * 64 + cidx;              // global col
                    const int hl = gc >> 5, d = gc & 31;
                    *(int4*)(outb + ((size_t)(b16 + h0 + hl) * 32 + d) * 128
                             + nc * 8) =
                        *(const int4*)(Ct + cidx * 136 + nc * 8);
                }
            }
        }
    } else {
        float* Cg = (float*)Cv;
#pragma unroll
        for (int j = 0; j < 4; ++j) {
            const int c = wn * 64 + j * 16 + lo;
            const float bv = bias[n0 + c];
#pragma unroll
            for (int i = 0; i < 4; ++i)
#pragma unroll
                for (int ii = 0; ii < 4; ++ii) {
                    const size_t r = m0 + wm * 64 + i * 16 + g * 4 + ii;
                    Cg[r * (size_t)Nn + n0 + c] = acc[i][j][ii] + bv;
                }
        }
    }
}

// ----------------------------------------------------------- attention ----
// One block (4 waves) per (b, h).  Inputs head-major: Q[b,h,n,d], K[b,h,n,d],
// Vt[b,h,d,n].  Q/K staged via global_load_lds with quarter-wave swizzle
// (64B rows); Vt reg-staged into padded [32][136].
// Union LDS 43520 B -> 3 blocks/CU.
__global__ __launch_bounds__(256) void attn_kernel(
    const u16* __restrict__ qbuf, const u16* __restrict__ kbuf,
    const u16* __restrict__ vtbuf, const float* __restrict__ epb,
    u16* __restrict__ aout)
{
    __shared__ __attribute__((aligned(16))) char smem[43520];
    u16 (*Vt)[136]      = (u16(*)[136])smem;                 // [32][136]
    char* Qs            = smem + 8704;                       // [128][32] swz
    char* Ks            = smem + 16896;                      // [128][32] swz
    u16 (*Ps)[32][136]  = (u16(*)[32][136])(smem + 8704);    // [4][32][136]
    u16 (*Os)[32]       = (u16(*)[32])smem;                  // [128][32]

    const int h = blockIdx.x >> 11;
    const int b = blockIdx.x & 2047;
    const int tid = threadIdx.x;
    const int lane = tid & 63, w = tid >> 6;
    const int lo = lane & 15, g = lane >> 4;
    const int wu = __builtin_amdgcn_readfirstlane(w);

    const size_t hb = (size_t)(b * 16 + h) * 4096;
    const u16* qp = qbuf + hb;
    const u16* kp = kbuf + hb;
    const u16* vp = vtbuf + hb;

    // Q/K via global_load_lds with inverse-swizzled source
    const int c8 = ((lane & 3) ^ ((lane >> 3) & 3)) * 8;
    const int rofs = (lane >> 2) * 32;
#pragma unroll
    for (int cc = 0; cc < 2; ++cc) {
        const int ch = wu * 2 + cc;
        GLDS16(qp + ch * 512 + rofs + c8, Qs + ch * 1024);
        GLDS16(kp + ch * 512 + rofs + c8, Ks + ch * 1024);
    }
    // Vt: coalesced int4 loads -> padded LDS rows
#pragma unroll
    for (int it = 0; it < 2; ++it) {
        const int idx = tid + it * 256;          // 0..511
        const int d = idx >> 4, nc = idx & 15;
        const int4 v = *(const int4*)(vp + idx * 8);
        *(int4*)(&Vt[d][nc * 8]) = v;
    }
    __syncthreads();

    const int r0 = w * 32;
    const int csw16 = (g ^ ((lo >> 1) & 3)) << 4;   // ds_read col swizzle

    // ---- S = Q @ K^T ----
    short8 aq[2], bk[8];
    aq[0] = *(const short8*)(Qs + (r0 + lo) * 64 + csw16);
    aq[1] = *(const short8*)(Qs + (r0 + 16 + lo) * 64 + csw16);
#pragma unroll
    for (int j = 0; j < 8; ++j)
        bk[j] = *(const short8*)(Ks + (j * 16 + lo) * 64 + csw16);

    f32x4 acc[2][8];
#pragma unroll
    for (int j = 0; j < 8; ++j) {
        f32x4 z = {0.f, 0.f, 0.f, 0.f};
        acc[0][j] = mfma16(aq[0], bk[j], z);
        acc[1][j] = mfma16(aq[1], bk[j], z);
    }

    // ---- bias + row max ----
    const float* eb = epb + (h << 14);
    float mrow[2][4], rsum[2][4];
#pragma unroll
    for (int mt = 0; mt < 2; ++mt)
#pragma unroll
        for (int ii = 0; ii < 4; ++ii) { mrow[mt][ii] = -1e30f; rsum[mt][ii] = 0.f; }

#pragma unroll
    for (int mt = 0; mt < 2; ++mt)
#pragma unroll
        for (int j = 0; j < 8; ++j)
#pragma unroll
            for (int ii = 0; ii < 4; ++ii) {
                const int r = r0 + mt * 16 + g * 4 + ii;
                const int c = j * 16 + lo;
                const float sv = acc[mt][j][ii] + eb[(r << 7) + c];
                acc[mt][j][ii] = sv;
                mrow[mt][ii] = fmaxf(mrow[mt][ii], sv);
            }
#pragma unroll
    for (int d = 1; d < 16; d <<= 1)
#pragma unroll
        for (int mt = 0; mt < 2; ++mt)
#pragma unroll
            for (int ii = 0; ii < 4; ++ii)
                mrow[mt][ii] = fmaxf(mrow[mt][ii], __shfl_xor(mrow[mt][ii], d, 64));

    __syncthreads();   // all waves done reading Qs/Ks -> Ps may overwrite

    // ---- exp -> Ps (per-wave private region), row sums ----
#pragma unroll
    for (int mt = 0; mt < 2; ++mt)
#pragma unroll
        for (int j = 0; j < 8; ++j)
#pragma unroll
            for (int ii = 0; ii < 4; ++ii) {
                const float p = __expf(acc[mt][j][ii] - mrow[mt][ii]);
                rsum[mt][ii] += p;
                Ps[w][mt * 16 + g * 4 + ii][j * 16 + lo] = f2bf(p);
            }
#pragma unroll
    for (int d = 1; d < 16; d <<= 1)
#pragma unroll
        for (int mt = 0; mt < 2; ++mt)
#pragma unroll
            for (int ii = 0; ii < 4; ++ii)
                rsum[mt][ii] += __shfl_xor(rsum[mt][ii], d, 64);

    // ---- O = P @ V ----
    f32x4 o[2][2] = {};
#pragma unroll
    for (int kk = 0; kk < 4; ++kk) {
        short8 av[2];
        av[0] = *(const short8*)(&Ps[w][lo][kk * 32 + g * 8]);
        av[1] = *(const short8*)(&Ps[w][16 + lo][kk * 32 + g * 8]);
#pragma unroll
        for (int dt = 0; dt < 2; ++dt) {
            const short8 bv = *(const short8*)(&Vt[dt * 16 + lo][kk * 32 + g * 8]);
            o[0][dt] = mfma16(av[0], bv, o[0][dt]);
            o[1][dt] = mfma16(av[1], bv, o[1][dt]);
        }
    }

    __syncthreads();   // all waves done reading Vt -> Os may overwrite

    // ---- normalize -> Os, coalesced int4 stores ----
#pragma unroll
    for (int mt = 0; mt < 2; ++mt)
#pragma unroll
        for (int dt = 0; dt < 2; ++dt)
#pragma unroll
            for (int ii = 0; ii < 4; ++ii)
                Os[r0 + mt * 16 + g * 4 + ii][dt * 16 + lo] =
                    f2bf(o[mt][dt][ii] / rsum[mt][ii]);
    __syncthreads();

    u16* op = aout + (size_t)b * 128 * 512 + h * 32;
#pragma unroll
    for (int it = 0; it < 2; ++it) {
        const int idx = tid + it * 256;          // 0..511
        const int r = idx >> 2, c = (idx & 3) * 8;
        *(int4*)(op + (size_t)r * 512 + c) = *(const int4*)(&Os[r][c]);
    }
}

// -------------------------------------------------------------- launch ----
extern "C" void kernel_launch(void* const* d_in, const int* in_sizes, int n_in,
                              void* d_out, int out_size, void* d_ws, size_t ws_size,
                              hipStream_t stream)
{
    const float* x      = (const float*)d_in[0];
    const float* qkv_w  = (const float*)d_in[1];
    const float* qkv_b  = (const float*)d_in[2];
    const float* proj_w = (const float*)d_in[3];
    const float* proj_b = (const float*)d_in[4];
    const float* btab   = (const float*)d_in[5];
    const int*   pidx   = (const int*)d_in[6];

    // workspace layout (bytes), total 1,076,887,552
    // xbf aliases attnbuf: x_bf16 is dead before attn writes its output.
    char* ws = (char*)d_ws;
    u16*   xbf      = (u16*)(ws);                        // 268,435,456
    u16*   attnbuf  = (u16*)(ws);                        // (alias)
    u16*   qkvw_bf  = (u16*)(ws + 268435456);            //   1,572,864
    u16*   projw_bf = (u16*)(ws + 270008320);            //     524,288
    float* epb      = (float*)(ws + 270532608);          //   1,048,576
    u16*   qbuf     = (u16*)(ws + 271581184);            // 268,435,456
    u16*   kbuf     = (u16*)(ws + 540016640);            // 268,435,456
    u16*   vtbuf    = (u16*)(ws + 808452096);            // 268,435,456

    const float qscale = 0.17677669529663687f;           // 32^-0.5

    cvt_x_kernel<<<dim3(8192), dim3(256), 0, stream>>>(
        (const float4*)x, (int4*)xbf);

    prep_kernel<<<dim3(3072), dim3(256), 0, stream>>>(
        qkv_w, proj_w, btab, pidx, qkvw_bf, projw_bf, epb);

    // QKV: [262144,512]bf16 @ [1536,512]bf16^T -> Q/K/Vt head-major buffers
    gemm_bt<true><<<dim3(2048 * 12), dim3(256), 0, stream>>>(
        xbf, qkvw_bf, qkv_b, qbuf, kbuf, vtbuf, 1536, 512, qscale);

    // fused window attention: 2048 windows x 16 heads
    attn_kernel<<<dim3(32768), dim3(256), 0, stream>>>(
        qbuf, kbuf, vtbuf, epb, attnbuf);

    // proj: [262144,512]bf16 @ [512,512]bf16^T -> f32 (+bias)
    gemm_bt<false><<<dim3(2048 * 4), dim3(256), 0, stream>>>(
        attnbuf, projw_bf, proj_b, d_out, nullptr, nullptr, 512, 512, 1.0f);
}

// Round 9
// 1287.116 us; speedup vs baseline: 1.7268x; 1.0875x over previous
//
#include <hip/hip_runtime.h>
#include <hip/hip_bf16.h>

// EarthAttention2D on MI355X (gfx950).
// B_WIN=2048, N=128, DIM=512, HEADS=16, hd=32, M = 2048*128 = 262144.
// Pipeline: cvt_x (x->bf16) + prep (weights->bf16, epb gather)
//        -> QKV GEMM (r2-proven loop: BK=64, single 32KiB buffer, GLDS both
//           operands, XOR-swizzled reads; r2-shaped single-pass epilogue ->
//           head-major Q/K/V[b,h,n,d])
//        -> fused window attention (gload_lds Q/K, in-kernel V transpose)
//        -> proj GEMM (same loop, f32 out).
//
// REGISTER-PRESSURE LESSON (r8): two-phase conditional epilogue pushed
// VGPR 76->100 -> 4 blocks/CU instead of 5 -> exactly 5/4 slower QKV
// (564->707us). Epilogue must be a single unconditional pass so acc
// liveness stays short. NEVER branch acc usage across barriers.
//
// LDS swizzle (BK=64, 128B rows): LDS[r][c16] = global[r][c16^(r&7)]
// (inverse swizzle on the GLDS *source*, linear dest - m173);
// ds_read addr (r*128+cb)^((lo&7)<<4) -> quarter-wave hits all 8 bank
// groups twice = conflict-free.

typedef short short8 __attribute__((ext_vector_type(8)));
typedef float f32x4 __attribute__((ext_vector_type(4)));
typedef unsigned short u16;
typedef unsigned int u32;

__device__ __forceinline__ u16 f2bf(float f) {
    __bf16 h = (__bf16)f;                    // RNE fptrunc -> v_cvt on gfx950
    union { __bf16 b; u16 u; } v; v.b = h;
    return v.u;
}

__device__ __forceinline__ f32x4 mfma16(short8 a, short8 b, f32x4 c) {
    return __builtin_amdgcn_mfma_f32_16x16x32_bf16(a, b, c, 0, 0, 0);
}

// async global->LDS, 16B per lane, dest = wave-uniform base + lane*16
#define GLDS16(gsrc, ldst)                                                  \
    __builtin_amdgcn_global_load_lds(                                       \
        (const __attribute__((address_space(1))) void*)(gsrc),              \
        (__attribute__((address_space(3))) void*)(ldst), 16, 0, 0)

// ---------------------------------------------------------------- cvt_x ----
__global__ __launch_bounds__(256) void cvt_x_kernel(
    const float4* __restrict__ xin, int4* __restrict__ xbf)
{
    int idx = blockIdx.x * 256 + threadIdx.x;           // unit = 8 floats
    for (; idx < 16777216; idx += 8192 * 256) {
        const float4 a = xin[idx * 2], b = xin[idx * 2 + 1];
        int4 o;
        o.x = (u32)f2bf(a.x) | ((u32)f2bf(a.y) << 16);
        o.y = (u32)f2bf(a.z) | ((u32)f2bf(a.w) << 16);
        o.z = (u32)f2bf(b.x) | ((u32)f2bf(b.y) << 16);
        o.w = (u32)f2bf(b.z) | ((u32)f2bf(b.w) << 16);
        xbf[idx] = o;
    }
}

// ---------------------------------------------------------------- prep ----
__global__ __launch_bounds__(256) void prep_kernel(
    const float* __restrict__ qkv_w, const float* __restrict__ proj_w,
    const float* __restrict__ btab, const int* __restrict__ pidx,
    u16* __restrict__ qkvw_bf, u16* __restrict__ projw_bf,
    float* __restrict__ epb)
{
    const int i = blockIdx.x * 256 + threadIdx.x;    // grid = 3072*256 = 786432
    qkvw_bf[i] = f2bf(qkv_w[i]);
    if (i < 512 * 512) projw_bf[i] = f2bf(proj_w[i]);
    if (i < 16 * 128 * 128) {
        const int rc = i & 16383, h = i >> 14;
        epb[i] = btab[pidx[rc] * 128 + 64 + h];      // bias_table[idx][TOW/2=4][h]
    }
}

// ---------------------------------------------------------------- GEMM ----
// C[M,Nn] = A[M,K] @ Bt[Nn,K]^T (+bias).  128x128 tile, BK=64, 4 waves.
// LDS: single buffer A[128][64] + B[128][64] = 32 KiB -> 5 blocks/CU.
// Loop (r2-proven): STAGE(0); { sync(drain); ds_read+32 MFMA; sync; STAGE }.
//
// EPI_QKV: tsel = bn>>2 (0=Q,1=K,2=V), 4 heads per tile; ALL tsel paths
// identical: single-pass [128][128] LDS restage (r2 pattern) then coalesced
// int4 scatter to out[((b*16+h)*128 + n)*32 + d], scale=qscale iff tsel==0.
// else: f32 direct stores (+bias) to Cv.

template<bool EPI_QKV>
__global__ __launch_bounds__(256) void gemm_bt(
    const u16* __restrict__ A, const u16* __restrict__ Bt,
    const float* __restrict__ bias, void* __restrict__ Cv,
    u16* __restrict__ kb, u16* __restrict__ vb,
    const int Nn, const int K, const float qscale)
{
    __shared__ __attribute__((aligned(16))) char sm[32768];
    char* As = sm;                  // [128] rows x 128B, swizzled content
    char* Bs = sm + 16384;

    const int tid = threadIdx.x;
    const int lane = tid & 63;
    const int w = tid >> 6;
    const int lo = lane & 15, g = lane >> 4;
    const int wm = w >> 1, wn = w & 1;
    const int wofs = __builtin_amdgcn_readfirstlane(w) * 1024;
    const int ntile = Nn >> 7;

    int wg = blockIdx.x;
    {   // bijective XCD swizzle (gridDim % 8 == 0 for all launches)
        const int cpx = gridDim.x >> 3;
        wg = (wg & 7) * cpx + (wg >> 3);
    }
    const int bm = wg / ntile, bn = wg % ntile;
    const size_t m0 = (size_t)bm << 7;
    const int n0 = bn << 7;
    const int nk = K >> 6;                               // 8

    // per-lane global source pointers: slot s = i*256+tid; r=s>>3, c16=s&7;
    // source col-chunk = c16 ^ (r&7)  (inverse swizzle, m173 pattern)
    const u16* pa[4];
    const u16* pb[4];
#pragma unroll
    for (int i = 0; i < 4; ++i) {
        const int s = i * 256 + tid;
        const int r = s >> 3, c16 = s & 7;
        const int csw = (c16 ^ (r & 7)) << 3;            // element offset
        pa[i] = A + (m0 + r) * (size_t)K + csw;
        pb[i] = Bt + (size_t)(n0 + r) * K + csw;
    }

#define STAGE(kt)                                                          \
    do {                                                                   \
        const int koff = (kt) * 64;                                        \
        _Pragma("unroll")                                                  \
        for (int i = 0; i < 4; ++i)                                        \
            GLDS16(pa[i] + koff, As + i * 4096 + wofs);                    \
        _Pragma("unroll")                                                  \
        for (int i = 0; i < 4; ++i)                                        \
            GLDS16(pb[i] + koff, Bs + i * 4096 + wofs);                    \
    } while (0)

    f32x4 acc[4][4] = {};

    STAGE(0);
    for (int kt = 0;;) {
        __syncthreads();            // drains vmcnt -> tile kt resident
#pragma unroll
        for (int kk = 0; kk < 2; ++kk) {
            short8 af[4], bq[4];
            const int cb = (kk * 4 + g) << 4;            // byte col-chunk
            const int sz = (lo & 7) << 4;                // row XOR swizzle
#pragma unroll
            for (int i = 0; i < 4; ++i) {
                const int ra = wm * 64 + i * 16 + lo;
                af[i] = *(const short8*)(As + ((ra * 128 + cb) ^ sz));
                const int rb = wn * 64 + i * 16 + lo;
                bq[i] = *(const short8*)(Bs + ((rb * 128 + cb) ^ sz));
            }
#pragma unroll
            for (int i = 0; i < 4; ++i)
#pragma unroll
                for (int j = 0; j < 4; ++j)
                    acc[i][j] = mfma16(af[i], bq[j], acc[i][j]);
        }
        if (++kt == nk) break;
        __syncthreads();            // all reads done; LDS free for next tile
        STAGE(kt);
    }
#undef STAGE

    if constexpr (EPI_QKV) {
        // r2-shaped single-pass epilogue: restage [128][128] bf16 (32 KiB),
        // then coalesced int4 scatter to head-major [b,h,n,32].
        __syncthreads();
        u16* Ct = (u16*)sm;
        const int b16 = ((int)(m0 >> 7)) * 16;
        const int tsel = bn >> 2;                        // 0=q,1=k,2=v (uniform)
        const int h0 = (bn & 3) << 2;
        u16* outb = (tsel == 0) ? (u16*)Cv : (tsel == 1) ? kb : vb;
        const float sc = (tsel == 0) ? qscale : 1.0f;
#pragma unroll
        for (int j = 0; j < 4; ++j) {
            const int c = wn * 64 + j * 16 + lo;
            const float bv = bias[n0 + c];
#pragma unroll
            for (int i = 0; i < 4; ++i)
#pragma unroll
                for (int ii = 0; ii < 4; ++ii) {
                    const int r = wm * 64 + i * 16 + g * 4 + ii;
                    Ct[r * 128 + c] = f2bf((acc[i][j][ii] + bv) * sc);
                }
        }
        __syncthreads();
#pragma unroll
        for (int it = 0; it < 8; ++it) {
            const int idx = it * 256 + tid;
            const int r = idx >> 4, s2 = idx & 15;
            const int hl = s2 >> 2, d0 = (s2 & 3) * 8;
            *(int4*)(outb + ((size_t)(b16 + h0 + hl) * 128 + r) * 32 + d0) =
                *(const int4*)(Ct + r * 128 + s2 * 8);
        }
    } else {
        float* Cg = (float*)Cv;
#pragma unroll
        for (int j = 0; j < 4; ++j) {
            const int c = wn * 64 + j * 16 + lo;
            const float bv = bias[n0 + c];
#pragma unroll
            for (int i = 0; i < 4; ++i)
#pragma unroll
                for (int ii = 0; ii < 4; ++ii) {
                    const size_t r = m0 + wm * 64 + i * 16 + g * 4 + ii;
                    Cg[r * (size_t)Nn + n0 + c] = acc[i][j][ii] + bv;
                }
        }
    }
}

// ----------------------------------------------------------- attention ----
// One block (4 waves) per (b, h).  Inputs head-major row-major:
// Q/K/V[b,h,n,d].  Q/K staged via global_load_lds with quarter-wave swizzle
// (64B rows); V loaded int4-coalesced and transposed into padded [32][136]
// via 8 scalar LDS writes (r2-proven).  Union LDS 43520 B -> 3 blocks/CU.
__global__ __launch_bounds__(256) void attn_kernel(
    const u16* __restrict__ qbuf, const u16* __restrict__ kbuf,
    const u16* __restrict__ vbuf, const float* __restrict__ epb,
    u16* __restrict__ aout)
{
    __shared__ __attribute__((aligned(16))) char smem[43520];
    u16 (*Vt)[136]      = (u16(*)[136])smem;                 // [32][136]
    char* Qs            = smem + 8704;                       // [128][32] swz
    char* Ks            = smem + 16896;                      // [128][32] swz
    u16 (*Ps)[32][136]  = (u16(*)[32][136])(smem + 8704);    // [4][32][136]
    u16 (*Os)[32]       = (u16(*)[32])smem;                  // [128][32]

    const int h = blockIdx.x >> 11;
    const int b = blockIdx.x & 2047;
    const int tid = threadIdx.x;
    const int lane = tid & 63, w = tid >> 6;
    const int lo = lane & 15, g = lane >> 4;
    const int wu = __builtin_amdgcn_readfirstlane(w);

    const size_t hb = (size_t)(b * 16 + h) * 4096;
    const u16* qp = qbuf + hb;
    const u16* kp = kbuf + hb;
    const u16* vp = vbuf + hb;

    // Q/K via global_load_lds with inverse-swizzled source
    const int c8 = ((lane & 3) ^ ((lane >> 3) & 3)) * 8;
    const int rofs = (lane >> 2) * 32;
#pragma unroll
    for (int cc = 0; cc < 2; ++cc) {
        const int ch = wu * 2 + cc;
        GLDS16(qp + ch * 512 + rofs + c8, Qs + ch * 1024);
        GLDS16(kp + ch * 512 + rofs + c8, Ks + ch * 1024);
    }
    // V: coalesced int4 loads, transpose via scalar LDS writes
#pragma unroll
    for (int it = 0; it < 2; ++it) {
        const int idx = tid + it * 256;          // 0..511
        const int n = idx >> 2, d8 = (idx & 3) * 8;
        union { int4 q; u16 u[8]; } vu;
        vu.q = *(const int4*)(vp + n * 32 + d8);
#pragma unroll
        for (int j = 0; j < 8; ++j) Vt[d8 + j][n] = vu.u[j];
    }
    __syncthreads();

    const int r0 = w * 32;
    const int csw16 = (g ^ ((lo >> 1) & 3)) << 4;   // ds_read col swizzle

    // ---- S = Q @ K^T ----
    short8 aq[2], bk[8];
    aq[0] = *(const short8*)(Qs + (r0 + lo) * 64 + csw16);
    aq[1] = *(const short8*)(Qs + (r0 + 16 + lo) * 64 + csw16);
#pragma unroll
    for (int j = 0; j < 8; ++j)
        bk[j] = *(const short8*)(Ks + (j * 16 + lo) * 64 + csw16);

    f32x4 acc[2][8];
#pragma unroll
    for (int j = 0; j < 8; ++j) {
        f32x4 z = {0.f, 0.f, 0.f, 0.f};
        acc[0][j] = mfma16(aq[0], bk[j], z);
        acc[1][j] = mfma16(aq[1], bk[j], z);
    }

    // ---- bias + row max ----
    const float* eb = epb + (h << 14);
    float mrow[2][4], rsum[2][4];
#pragma unroll
    for (int mt = 0; mt < 2; ++mt)
#pragma unroll
        for (int ii = 0; ii < 4; ++ii) { mrow[mt][ii] = -1e30f; rsum[mt][ii] = 0.f; }

#pragma unroll
    for (int mt = 0; mt < 2; ++mt)
#pragma unroll
        for (int j = 0; j < 8; ++j)
#pragma unroll
            for (int ii = 0; ii < 4; ++ii) {
                const int r = r0 + mt * 16 + g * 4 + ii;
                const int c = j * 16 + lo;
                const float sv = acc[mt][j][ii] + eb[(r << 7) + c];
                acc[mt][j][ii] = sv;
                mrow[mt][ii] = fmaxf(mrow[mt][ii], sv);
            }
#pragma unroll
    for (int d = 1; d < 16; d <<= 1)
#pragma unroll
        for (int mt = 0; mt < 2; ++mt)
#pragma unroll
            for (int ii = 0; ii < 4; ++ii)
                mrow[mt][ii] = fmaxf(mrow[mt][ii], __shfl_xor(mrow[mt][ii], d, 64));

    __syncthreads();   // all waves done reading Qs/Ks -> Ps may overwrite

    // ---- exp -> Ps (per-wave private region), row sums ----
#pragma unroll
    for (int mt = 0; mt < 2; ++mt)
#pragma unroll
        for (int j = 0; j < 8; ++j)
#pragma unroll
            for (int ii = 0; ii < 4; ++ii) {
                const float p = __expf(acc[mt][j][ii] - mrow[mt][ii]);
                rsum[mt][ii] += p;
                Ps[w][mt * 16 + g * 4 + ii][j * 16 + lo] = f2bf(p);
            }
#pragma unroll
    for (int d = 1; d < 16; d <<= 1)
#pragma unroll
        for (int mt = 0; mt < 2; ++mt)
#pragma unroll
            for (int ii = 0; ii < 4; ++ii)
                rsum[mt][ii] += __shfl_xor(rsum[mt][ii], d, 64);

    // ---- O = P @ V ----
    f32x4 o[2][2] = {};
#pragma unroll
    for (int kk = 0; kk < 4; ++kk) {
        short8 av[2];
        av[0] = *(const short8*)(&Ps[w][lo][kk * 32 + g * 8]);
        av[1] = *(const short8*)(&Ps[w][16 + lo][kk * 32 + g * 8]);
#pragma unroll
        for (int dt = 0; dt < 2; ++dt) {
            const short8 bv = *(const short8*)(&Vt[dt * 16 + lo][kk * 32 + g * 8]);
            o[0][dt] = mfma16(av[0], bv, o[0][dt]);
            o[1][dt] = mfma16(av[1], bv, o[1][dt]);
        }
    }

    __syncthreads();   // all waves done reading Vt -> Os may overwrite

    // ---- normalize -> Os, coalesced int4 stores ----
#pragma unroll
    for (int mt = 0; mt < 2; ++mt)
#pragma unroll
        for (int dt = 0; dt < 2; ++dt)
#pragma unroll
            for (int ii = 0; ii < 4; ++ii)
                Os[r0 + mt * 16 + g * 4 + ii][dt * 16 + lo] =
                    f2bf(o[mt][dt][ii] / rsum[mt][ii]);
    __syncthreads();

    u16* op = aout + (size_t)b * 128 * 512 + h * 32;
#pragma unroll
    for (int it = 0; it < 2; ++it) {
        const int idx = tid + it * 256;          // 0..511
        const int r = idx >> 2, c = (idx & 3) * 8;
        *(int4*)(op + (size_t)r * 512 + c) = *(const int4*)(&Os[r][c]);
    }
}

// -------------------------------------------------------------- launch ----
extern "C" void kernel_launch(void* const* d_in, const int* in_sizes, int n_in,
                              void* d_out, int out_size, void* d_ws, size_t ws_size,
                              hipStream_t stream)
{
    const float* x      = (const float*)d_in[0];
    const float* qkv_w  = (const float*)d_in[1];
    const float* qkv_b  = (const float*)d_in[2];
    const float* proj_w = (const float*)d_in[3];
    const float* proj_b = (const float*)d_in[4];
    const float* btab   = (const float*)d_in[5];
    const int*   pidx   = (const int*)d_in[6];

    // workspace layout (bytes), total 1,076,887,552
    // xbf aliases attnbuf: x_bf16 is dead before attn writes its output.
    char* ws = (char*)d_ws;
    u16*   xbf      = (u16*)(ws);                        // 268,435,456
    u16*   attnbuf  = (u16*)(ws);                        // (alias)
    u16*   qkvw_bf  = (u16*)(ws + 268435456);            //   1,572,864
    u16*   projw_bf = (u16*)(ws + 270008320);            //     524,288
    float* epb      = (float*)(ws + 270532608);          //   1,048,576
    u16*   qbuf     = (u16*)(ws + 271581184);            // 268,435,456
    u16*   kbuf     = (u16*)(ws + 540016640);            // 268,435,456
    u16*   vbuf     = (u16*)(ws + 808452096);            // 268,435,456

    const float qscale = 0.17677669529663687f;           // 32^-0.5

    cvt_x_kernel<<<dim3(8192), dim3(256), 0, stream>>>(
        (const float4*)x, (int4*)xbf);

    prep_kernel<<<dim3(3072), dim3(256), 0, stream>>>(
        qkv_w, proj_w, btab, pidx, qkvw_bf, projw_bf, epb);

    // QKV: [262144,512]bf16 @ [1536,512]bf16^T -> Q/K/V head-major buffers
    gemm_bt<true><<<dim3(2048 * 12), dim3(256), 0, stream>>>(
        xbf, qkvw_bf, qkv_b, qbuf, kbuf, vbuf, 1536, 512, qscale);

    // fused window attention: 2048 windows x 16 heads
    attn_kernel<<<dim3(32768), dim3(256), 0, stream>>>(
        qbuf, kbuf, vbuf, epb, attnbuf);

    // proj: [262144,512]bf16 @ [512,512]bf16^T -> f32 (+bias)
    gemm_bt<false><<<dim3(2048 * 4), dim3(256), 0, stream>>>(
        attnbuf, projw_bf, proj_b, d_out, nullptr, nullptr, 512, 512, 1.0f);
}